// Round 8
// baseline (241.070 us; speedup 1.0000x reference)
//
#include <hip/hip_runtime.h>

// Band-streaming IDCT: each workgroup processes 2 consecutive 8-row bands.
// KEY LAYOUT FACT: an 8-row band of a 1024-wide image is 32 KB of CONTIGUOUS
// memory. All previous versions (78-88 us, ~2.5 TB/s) read/wrote 256B-2KB
// chunks at 4 KB stride from thousands of concurrent work units -> DRAM
// row-buffer thrash. The 6.9 TB/s fill and 6.3 TB/s copy stream contiguously.
// This version makes every global access stream linear: wg reads 64 KB
// sequentially, writes 64 KB sequentially (non-temporal).
//
// Still ZERO barriers: wave wv loads f4-cols [64wv,64wv+64) of each band row
// (phase 1, linear), computes exactly the 32 blocks in those columns
// (phase 2/3), and stores the same columns back (phase 4). All LDS
// dependencies are wave-internal -> compiler lgkmcnt waits only.
//
// LDS row stride 1028 floats (1028 % 32 == 4):
//  - P1/P4 dense 1KB-per-wave-instr access: uniform 8 words/bank (minimum).
//  - P3 row writeback bank = (4i + 8b3 + 4h + w) % 32: exactly uniform
//    8 words/bank -> conflict-free (the unpadded stride 1024 drops i from
//    the bank index -> 8-way conflict).
//  - P2 reads are 8-lane broadcasts, ~free.

typedef float f32x4 __attribute__((ext_vector_type(4)));

__global__ __launch_bounds__(256, 4) void bidct_kernel(
    const float* __restrict__ x, const float* __restrict__ qt,
    const float* __restrict__ mtx, float* __restrict__ out)
{
    __shared__ float tile[8 * 1028];   // 8 rows x 1028 floats = 32.9 KB

    const int t  = threadIdx.x;
    const int wv = t >> 6;             // wave 0..3
    const int l  = t & 63;             // lane
    const int b3 = l >> 3;             // block-within-pass 0..7
    const int i  = l & 7;              // row within block
    const int c4 = wv * 64 + l;        // this thread's f4 column 0..255

    float mcol[8];                     // M[j][i], lane-varying (L1 table)
#pragma unroll
    for (int j = 0; j < 8; ++j) mcol[j] = mtx[j * 8 + i];

    for (int s = 0; s < 2; ++s) {
        const int band = blockIdx.x * 2 + s;          // 0..4095 (8-row bands)
        const size_t base = (size_t)band * 8192;      // floats; bands contiguous

        // ---- Phase 1: linear global -> LDS (8 loads in flight) ----
        float4 v[8];
#pragma unroll
        for (int k = 0; k < 8; ++k)
            v[k] = *reinterpret_cast<const float4*>(x + base + k * 1024 + c4 * 4);
#pragma unroll
        for (int k = 0; k < 8; ++k)
            *reinterpret_cast<float4*>(&tile[k * 1028 + c4 * 4]) = v[k];

        // ---- Phase 2/3: 4 passes, 8 blocks/pass/wave, all wave-local ----
#pragma unroll
        for (int p = 0; p < 4; ++p) {
            const int B = wv * 32 + p * 8 + b3;       // block 0..127 in band

            float T[8] = {0.f, 0.f, 0.f, 0.f, 0.f, 0.f, 0.f, 0.f};
#pragma unroll
            for (int j = 0; j < 8; ++j) {
                const float4 xa = *reinterpret_cast<const float4*>(&tile[j * 1028 + B * 8]);
                const float4 xb = *reinterpret_cast<const float4*>(&tile[j * 1028 + B * 8 + 4]);
                const float mj = mcol[j];
                T[0] = fmaf(mj, xa.x * qt[j * 8 + 0], T[0]);  // qt idx uniform -> SGPR
                T[1] = fmaf(mj, xa.y * qt[j * 8 + 1], T[1]);
                T[2] = fmaf(mj, xa.z * qt[j * 8 + 2], T[2]);
                T[3] = fmaf(mj, xa.w * qt[j * 8 + 3], T[3]);
                T[4] = fmaf(mj, xb.x * qt[j * 8 + 4], T[4]);
                T[5] = fmaf(mj, xb.y * qt[j * 8 + 5], T[5]);
                T[6] = fmaf(mj, xb.z * qt[j * 8 + 6], T[6]);
                T[7] = fmaf(mj, xb.w * qt[j * 8 + 7], T[7]);
            }

            float o[8] = {128.f, 128.f, 128.f, 128.f, 128.f, 128.f, 128.f, 128.f};
#pragma unroll
            for (int k = 0; k < 8; ++k) {
                const float tk = T[k];
#pragma unroll
                for (int lc = 0; lc < 8; ++lc)
                    o[lc] = fmaf(tk, mtx[k * 8 + lc], o[lc]); // uniform -> SGPR
            }

            *reinterpret_cast<float4*>(&tile[i * 1028 + B * 8])     =
                make_float4(o[0], o[1], o[2], o[3]);
            *reinterpret_cast<float4*>(&tile[i * 1028 + B * 8 + 4]) =
                make_float4(o[4], o[5], o[6], o[7]);
        }

        // ---- Phase 4: linear LDS -> global, non-temporal ----
#pragma unroll
        for (int k = 0; k < 8; ++k) {
            const float4 w4 = *reinterpret_cast<const float4*>(&tile[k * 1028 + c4 * 4]);
            f32x4 nv; nv.x = w4.x; nv.y = w4.y; nv.z = w4.z; nv.w = w4.w;
            __builtin_nontemporal_store(nv,
                reinterpret_cast<f32x4*>(out + base + k * 1024 + c4 * 4));
        }
    }
}

extern "C" void kernel_launch(void* const* d_in, const int* in_sizes, int n_in,
                              void* d_out, int out_size, void* d_ws, size_t ws_size,
                              hipStream_t stream) {
    const float* x   = (const float*)d_in[0];
    const float* qt  = (const float*)d_in[1];
    const float* mtx = (const float*)d_in[2];
    float*       out = (float*)d_out;

    // out_size in floats; band = 8192 floats; each wg streams 2 bands (64 KB)
    const int bands = out_size / 8192;       // 4096
    const int grid  = bands / 2;             // 2048 workgroups
    bidct_kernel<<<grid, 256, 0, stream>>>(x, qt, mtx, out);
}